// Round 15
// baseline (187.721 us; speedup 1.0000x reference)
//
#include <hip/hip_runtime.h>
#include <hip/hip_bf16.h>
#include <math.h>

typedef __hip_bfloat16 bf16;
typedef __attribute__((ext_vector_type(8))) short bf16x8;
typedef __attribute__((ext_vector_type(4))) short short4v;
typedef __attribute__((ext_vector_type(4))) float f32x4;
typedef __attribute__((ext_vector_type(4))) unsigned int u32x4;

static constexpr int B = 2, S = 2048, D = 2048, H = 32, HK = 8, HD = 64;
static constexpr int M = B * S;           // 4096 tokens
static constexpr int NKV = HK * HD;       // 512
static constexpr int QKV3 = D + 2 * NKV;  // 3072 fused Q|K|V width
static constexpr float SCALE2 = 0.125f * 1.44269504f;  // folded into Q-rope in attn

__device__ __forceinline__ short bfbits(float x) {
  bf16 h = __float2bfloat16(x);
  return *reinterpret_cast<short*>(&h);
}

__device__ __forceinline__ float bf2f(short bits) {
  unsigned int u = ((unsigned int)(unsigned short)bits) << 16;
  return __builtin_bit_cast(float, u);
}

__device__ __forceinline__ void gl_lds16(const bf16* gp, bf16* lp) {
  __builtin_amdgcn_global_load_lds(
      (const __attribute__((address_space(1))) unsigned int*)(const void*)gp,
      (__attribute__((address_space(3))) unsigned int*)(void*)lp, 16, 0, 0);
}

// ---------------- fused cast fp32 -> bf16, 5 source regions ----------------
struct alignas(8) bf4 { bf16 v[4]; };
static constexpr int N4_X  = M * D / 4;        // 2097152
static constexpr int N4_WQ = D * D / 4;        // 1048576
static constexpr int N4_WK = NKV * D / 4;      // 262144
static constexpr int E0 = N4_X;
static constexpr int E1 = E0 + N4_WQ;
static constexpr int E2 = E1 + N4_WK;
static constexpr int E3 = E2 + N4_WK;
static constexpr int E4 = E3 + N4_WQ;
__global__ __launch_bounds__(256) void cast_all_kernel(const float* __restrict__ x,
                                                       const float* __restrict__ wq,
                                                       const float* __restrict__ wk,
                                                       const float* __restrict__ wv,
                                                       const float* __restrict__ wo,
                                                       bf16* __restrict__ xb,
                                                       bf16* __restrict__ wqkv,
                                                       bf16* __restrict__ wob) {
  int i = blockIdx.x * 256 + threadIdx.x;
  int stride = gridDim.x * 256;
  for (; i < E4; i += stride) {
    const float* s; bf16* d; int j;
    if (i < E0)      { s = x;  d = xb;   j = i; }
    else if (i < E1) { s = wq; d = wqkv; j = i - E0; }
    else if (i < E2) { s = wk; d = wqkv + (size_t)N4_WQ * 4; j = i - E1; }
    else if (i < E3) { s = wv; d = wqkv + (size_t)(N4_WQ + N4_WK) * 4; j = i - E2; }
    else             { s = wo; d = wob;  j = i - E3; }
    float4 f = reinterpret_cast<const float4*>(s)[j];
    bf4 o;
    o.v[0] = __float2bfloat16(f.x);
    o.v[1] = __float2bfloat16(f.y);
    o.v[2] = __float2bfloat16(f.z);
    o.v[3] = __float2bfloat16(f.w);
    reinterpret_cast<bf4*>(d)[j] = o;
  }
}

// ---------------- QKV GEMM 128x128 with fused K-rope + V-transpose epilogue --
// C[M][3072] = A[M][K] @ Wt[3072][K]^T.
// Q cols [0,2048): plain bf16 store to qkv.
// K cols [2048,2560): RoPE applied in-register (pairs are acc[m][n]/acc[m][n+2]
//   since each wave's 4 n-slots span exactly one 64-ch head), store to qkv.
// V cols [2560,3072): store DIRECTLY into vt[b][hk][hd][S] slot-permuted
//   layout (4 consecutive tokens = 4 consecutive pos -> one 8B store).
__global__ __launch_bounds__(256) void gemm_qkv_kernel(const bf16* __restrict__ A,
                                                       const bf16* __restrict__ Wt,
                                                       bf16* __restrict__ qkv,
                                                       bf16* __restrict__ vt,
                                                       const float* __restrict__ cosb,
                                                       const float* __restrict__ sinb) {
  __shared__ __align__(16) bf16 As[128][64];
  __shared__ __align__(16) bf16 Bs[128][64];
  const int tid = threadIdx.x;
  const int lane = tid & 63;
  const int w = tid >> 6;
  const int wm = w >> 1, wn = w & 1;
  const int r16 = lane & 15, g = lane >> 4;
  const int bm = blockIdx.y, bn = blockIdx.x;
  f32x4 acc[4][4] = {};

  const int nk = D >> 6;
  for (int kt = 0; kt < nk; ++kt) {
    __syncthreads();
#pragma unroll
    for (int i = 0; i < 4; ++i) {
      int u = tid + i * 256;           // 0..1023 : 128 rows x 8 16B-chunks
      int rr = u >> 3, c8 = u & 7;
      int c8s = c8 ^ (rr & 7);         // pre-swizzled source chunk
      gl_lds16(&A[(size_t)(bm * 128 + rr) * D + kt * 64 + c8s * 8], &As[0][0] + (size_t)u * 8);
      gl_lds16(&Wt[(size_t)(bn * 128 + rr) * D + kt * 64 + c8s * 8], &Bs[0][0] + (size_t)u * 8);
    }
    __syncthreads();
#pragma unroll
    for (int kc = 0; kc < 2; ++kc) {
      bf16x8 af[4], bfr[4];
      const int kq = kc * 4 + g;
#pragma unroll
      for (int m = 0; m < 4; ++m) {
        int ra = wm * 64 + m * 16 + r16;
        af[m] = *reinterpret_cast<const bf16x8*>(&As[ra][(kq ^ (ra & 7)) * 8]);
        int rb = wn * 64 + m * 16 + r16;
        bfr[m] = *reinterpret_cast<const bf16x8*>(&Bs[rb][(kq ^ (rb & 7)) * 8]);
      }
#pragma unroll
      for (int m = 0; m < 4; ++m)
#pragma unroll
        for (int n = 0; n < 4; ++n)
          acc[m][n] = __builtin_amdgcn_mfma_f32_16x16x32_bf16(af[m], bfr[n], acc[m][n], 0, 0, 0);
    }
  }

  const int row0 = bm * 128 + wm * 64 + g * 4;
  const int col0 = bn * 128 + wn * 64 + r16;
  if (col0 < D) {
    // ---- Q region: plain store
#pragma unroll
    for (int m = 0; m < 4; ++m)
#pragma unroll
      for (int n = 0; n < 4; ++n)
#pragma unroll
        for (int j = 0; j < 4; ++j)
          qkv[(size_t)(row0 + m * 16 + j) * QKV3 + col0 + n * 16] =
              __float2bfloat16(acc[m][n][j]);
  } else if (col0 < D + NKV) {
    // ---- K region: fused RoPE. i0 = r16 (n=0 pairs n=2), i1 = 16+r16 (n=1 / n=3)
#pragma unroll
    for (int m = 0; m < 4; ++m)
#pragma unroll
      for (int j = 0; j < 4; ++j) {
        const int tok = row0 + m * 16 + j;
        const int s = tok & (S - 1);
        const float c0 = cosb[(size_t)s * HD + r16];
        const float c1 = cosb[(size_t)s * HD + 16 + r16];
        const float s0 = sinb[(size_t)s * HD + r16];
        const float s1 = sinb[(size_t)s * HD + 16 + r16];
        const float x0a = acc[m][0][j], x1a = acc[m][2][j];
        const float x0b = acc[m][1][j], x1b = acc[m][3][j];
        bf16* rp = &qkv[(size_t)tok * QKV3 + col0];
        rp[0]  = __float2bfloat16(x0a * c0 - x1a * s0);
        rp[16] = __float2bfloat16(x0b * c1 - x1b * s1);
        rp[32] = __float2bfloat16(x1a * c0 + x0a * s0);
        rp[48] = __float2bfloat16(x1b * c1 + x0b * s1);
      }
  } else {
    // ---- V region: transposed + slot-permuted store into vt
#pragma unroll
    for (int m = 0; m < 4; ++m) {
      const int tok = row0 + m * 16;         // j-base (4-aligned within 32-block)
      const int b = tok >> 11;
      const int sg = tok & (S - 1);
      const int blk = sg >> 5, kvl0 = sg & 31;
      const int pos0 = ((kvl0 >> 2) & 3) * 8 + ((kvl0 >> 4) << 2);  // +j contiguous
#pragma unroll
      for (int n = 0; n < 4; ++n) {
        const int vch = col0 + n * 16 - (D + NKV);
        const int hk = vch >> 6, hd = vch & 63;
        short4v ov;
        ov[0] = bfbits(acc[m][n][0]);
        ov[1] = bfbits(acc[m][n][1]);
        ov[2] = bfbits(acc[m][n][2]);
        ov[3] = bfbits(acc[m][n][3]);
        *reinterpret_cast<short4v*>(
            &vt[(((size_t)b * HK + hk) * HD + hd) * S + blk * 32 + pos0]) = ov;
      }
    }
  }
}

// ---------------- GEMM 128x128 (O-projection): C = A @ Bt^T, f32 out --------
template <bool OUT_F32>
__global__ __launch_bounds__(256) void gemm_bt_kernel(const bf16* __restrict__ A,
                                                      const bf16* __restrict__ Bt,
                                                      void* __restrict__ C,
                                                      int Ndim, int Kdim) {
  __shared__ __align__(16) bf16 As[128][64];
  __shared__ __align__(16) bf16 Bs[128][64];
  const int tid = threadIdx.x;
  const int lane = tid & 63;
  const int w = tid >> 6;
  const int wm = w >> 1, wn = w & 1;
  const int r16 = lane & 15, g = lane >> 4;
  const int bm = blockIdx.y, bn = blockIdx.x;
  f32x4 acc[4][4] = {};

  const int nk = Kdim >> 6;
  for (int kt = 0; kt < nk; ++kt) {
    __syncthreads();
#pragma unroll
    for (int i = 0; i < 4; ++i) {
      int u = tid + i * 256;           // 0..1023 : 128 rows x 8 16B-chunks
      int rr = u >> 3, c8 = u & 7;
      int c8s = c8 ^ (rr & 7);         // pre-swizzled source chunk
      gl_lds16(&A[(size_t)(bm * 128 + rr) * Kdim + kt * 64 + c8s * 8], &As[0][0] + (size_t)u * 8);
      gl_lds16(&Bt[(size_t)(bn * 128 + rr) * Kdim + kt * 64 + c8s * 8], &Bs[0][0] + (size_t)u * 8);
    }
    __syncthreads();
#pragma unroll
    for (int kc = 0; kc < 2; ++kc) {
      bf16x8 af[4], bfr[4];
      const int kq = kc * 4 + g;       // logical 16B-chunk index within BK=64
#pragma unroll
      for (int m = 0; m < 4; ++m) {
        int ra = wm * 64 + m * 16 + r16;
        af[m] = *reinterpret_cast<const bf16x8*>(&As[ra][(kq ^ (ra & 7)) * 8]);
        int rb = wn * 64 + m * 16 + r16;
        bfr[m] = *reinterpret_cast<const bf16x8*>(&Bs[rb][(kq ^ (rb & 7)) * 8]);
      }
#pragma unroll
      for (int m = 0; m < 4; ++m)
#pragma unroll
        for (int n = 0; n < 4; ++n)
          acc[m][n] = __builtin_amdgcn_mfma_f32_16x16x32_bf16(af[m], bfr[n], acc[m][n], 0, 0, 0);
    }
  }
  const int row0 = bm * 128 + wm * 64 + g * 4;
  const int col0 = bn * 128 + wn * 64 + r16;
#pragma unroll
  for (int m = 0; m < 4; ++m)
#pragma unroll
    for (int n = 0; n < 4; ++n)
#pragma unroll
      for (int j = 0; j < 4; ++j) {
        size_t idx = (size_t)(row0 + m * 16 + j) * Ndim + col0 + n * 16;
        if (OUT_F32)
          reinterpret_cast<float*>(C)[idx] = acc[m][n][j];
        else
          reinterpret_cast<bf16*>(C)[idx] = __float2bfloat16(acc[m][n][j]);
      }
}

// ---------------- causal flash attention (GQA), 4-wave LDS-staged ------------
__global__ __launch_bounds__(256, 2) void attn_kernel(const bf16* __restrict__ qkv,
                                                      const bf16* __restrict__ vt,
                                                      const float* __restrict__ cosb,
                                                      const float* __restrict__ sinb,
                                                      bf16* __restrict__ ao) {
  __shared__ __align__(16) bf16 Ksh[2][64 * 64];
  __shared__ __align__(16) bf16 Vsh[2][64 * 64];
  const int u = blockIdx.x;        // 0..31
  const int y = blockIdx.y;        // b*HK + hk
  const int b = y >> 3, hk = y & 7;
  const int tid = threadIdx.x;
  const int w = tid >> 6;
  const int h = hk * 4 + w;        // this wave's head
  const int lane = tid & 63;
  const int r = lane & 15, g = lane >> 4;

  const bf16* qp  = qkv + ((size_t)b * S) * QKV3 + h * HD;         // Q (raw)
  const bf16* kvp = qkv + ((size_t)b * S) * QKV3 + D + hk * HD;    // K rows (stride 3072)
  const bf16* vtp = vt + (((size_t)b * HK + hk) * HD) * S;         // V^T rows (stride S)
  const int srow = tid >> 3;       // staging: 0..31 (+32 per iter)
  const int sc8 = tid & 7;

  bf16x8 ones;
#pragma unroll
  for (int j = 0; j < 8; ++j) ones[j] = (short)0x3F80;  // bf16 1.0

  auto stage64 = [&](int buf, int kv0) {
#pragma unroll
    for (int i = 0; i < 2; ++i) {
      int rr = srow + i * 32;
      int cs = sc8 ^ (rr & 7);
      gl_lds16(&kvp[(size_t)(kv0 + rr) * QKV3 + cs * 8], &Ksh[buf][((size_t)rr * 8 + sc8) * 8]);
    }
#pragma unroll
    for (int i = 0; i < 2; ++i) {
      int rr = srow + i * 32;
      int cs = sc8 ^ (rr & 7);
      gl_lds16(&vtp[(size_t)rr * S + kv0 + cs * 8], &Vsh[buf][((size_t)rr * 8 + sc8) * 8]);
    }
  };

  for (int pass = 0; pass < 2; ++pass) {
    const int qb = pass ? (2016 - u * 32) : (u * 32);
    // Q fragments (B-operand of S^T): col=q=r, k=hd=g*8+j (+32*hc)
    bf16x8 qfr[2][2];
#pragma unroll
    for (int qq = 0; qq < 2; ++qq) {
      const int srowq = qb + qq * 16 + r;
      bf16x8 f0 = *reinterpret_cast<const bf16x8*>(&qp[(size_t)srowq * QKV3 + g * 8]);
      bf16x8 f1 = *reinterpret_cast<const bf16x8*>(&qp[(size_t)srowq * QKV3 + 32 + g * 8]);
      float4 c0 = reinterpret_cast<const float4*>(&cosb[(size_t)srowq * HD + g * 8])[0];
      float4 c1 = reinterpret_cast<const float4*>(&cosb[(size_t)srowq * HD + g * 8])[1];
      float4 s0 = reinterpret_cast<const float4*>(&sinb[(size_t)srowq * HD + g * 8])[0];
      float4 s1 = reinterpret_cast<const float4*>(&sinb[(size_t)srowq * HD + g * 8])[1];
      float cc[8] = {c0.x, c0.y, c0.z, c0.w, c1.x, c1.y, c1.z, c1.w};
      float ss[8] = {s0.x, s0.y, s0.z, s0.w, s1.x, s1.y, s1.z, s1.w};
#pragma unroll
      for (int j = 0; j < 8; ++j) {
        float x0 = bf2f(f0[j]), x1 = bf2f(f1[j]);
        qfr[qq][0][j] = bfbits((x0 * cc[j] - x1 * ss[j]) * SCALE2);
        qfr[qq][1][j] = bfbits((x1 * cc[j] + x0 * ss[j]) * SCALE2);
      }
    }

    f32x4 o[4][2] = {};
    f32x4 ol[2] = {};                // l accumulator (all rows identical)
    const int kv_end = qb + 32;
    const int nch = (kv_end + 63) >> 6;

    // one chunk: CUR is a literal at each call site -> LDS addresses hoist
    auto chunk = [&](int CUR, int cc, bool lastc) {
      const int kv0 = cc * 64;
      if (!lastc) stage64(CUR ^ 1, kv0 + 64);
      // S^T[kv][q] (exp2 domain): A=K (row=kv, k=hd), B=Q
      f32x4 scv[4][2] = {};
      __builtin_amdgcn_s_setprio(1);
#pragma unroll
      for (int f = 0; f < 4; ++f) {
        const int row = f * 16 + r;
#pragma unroll
        for (int hc = 0; hc < 2; ++hc) {
          bf16x8 kf = *reinterpret_cast<const bf16x8*>(
              &Ksh[CUR][(size_t)row * 64 + (((hc * 4 + g) ^ (r & 7)) * 8)]);
          scv[f][0] = __builtin_amdgcn_mfma_f32_16x16x32_bf16(kf, qfr[0][hc], scv[f][0], 0, 0, 0);
          scv[f][1] = __builtin_amdgcn_mfma_f32_16x16x32_bf16(kf, qfr[1][hc], scv[f][1], 0, 0, 0);
        }
      }
      __builtin_amdgcn_s_setprio(0);
      // causal mask (no max tracking: scores bounded)
      if (lastc) {
#pragma unroll
        for (int qq = 0; qq < 2; ++qq) {
          const int lim = qb + qq * 16 + r - kv0;
#pragma unroll
          for (int f = 0; f < 4; ++f)
#pragma unroll
            for (int j = 0; j < 4; ++j)
              if (f * 16 + g * 4 + j > lim) scv[f][qq][j] = -1e30f;
        }
      }
      // P = exp2(S^T), truncating pair-pack + PV + l per 32-kv block
#pragma unroll
      for (int blk = 0; blk < 2; ++blk) {
        u32x4 pk0, pk1;
#pragma unroll
        for (int pj = 0; pj < 4; ++pj) {
          const int f = blk * 2 + (pj >> 1);
          const int j0 = (pj & 1) * 2;
          float a0 = __builtin_amdgcn_exp2f(scv[f][0][j0]);
          float a1 = __builtin_amdgcn_exp2f(scv[f][0][j0 + 1]);
          pk0[pj] = (__builtin_bit_cast(unsigned int, a0) >> 16) |
                    (__builtin_bit_cast(unsigned int, a1) & 0xffff0000u);
          float b0 = __builtin_amdgcn_exp2f(scv[f][1][j0]);
          float b1 = __builtin_amdgcn_exp2f(scv[f][1][j0 + 1]);
          pk1[pj] = (__builtin_bit_cast(unsigned int, b0) >> 16) |
                    (__builtin_bit_cast(unsigned int, b1) & 0xffff0000u);
        }
        bf16x8 pb0 = __builtin_bit_cast(bf16x8, pk0);
        bf16x8 pb1 = __builtin_bit_cast(bf16x8, pk1);
        __builtin_amdgcn_s_setprio(1);
        ol[0] = __builtin_amdgcn_mfma_f32_16x16x32_bf16(ones, pb0, ol[0], 0, 0, 0);
        ol[1] = __builtin_amdgcn_mfma_f32_16x16x32_bf16(ones, pb1, ol[1], 0, 0, 0);
#pragma unroll
        for (int d = 0; d < 4; ++d) {
          bf16x8 vf = *reinterpret_cast<const bf16x8*>(
              &Vsh[CUR][(size_t)(d * 16 + r) * 64 + (((blk * 4 + g) ^ (r & 7)) * 8)]);
          o[d][0] = __builtin_amdgcn_mfma_f32_16x16x32_bf16(vf, pb0, o[d][0], 0, 0, 0);
          o[d][1] = __builtin_amdgcn_mfma_f32_16x16x32_bf16(vf, pb1, o[d][1], 0, 0, 0);
        }
        __builtin_amdgcn_s_setprio(0);
      }
      __syncthreads();   // drains stage(cc+1) + guards buffer reuse
    };

    stage64(0, 0);
    __syncthreads();
    int c = 0;
    for (; c + 2 <= nch; c += 2) {
      chunk(0, c, c == nch - 1);
      chunk(1, c + 1, c + 1 == nch - 1);
    }
    if (c < nch) chunk(0, c, true);

    // epilogue: l lives in every lane (all MFMA rows identical)
#pragma unroll
    for (int qq = 0; qq < 2; ++qq) {
      float inv = 1.0f / ol[qq][0];
#pragma unroll
      for (int d = 0; d < 4; ++d) {
        short4v ov;
        ov[0] = bfbits(o[d][qq][0] * inv);
        ov[1] = bfbits(o[d][qq][1] * inv);
        ov[2] = bfbits(o[d][qq][2] * inv);
        ov[3] = bfbits(o[d][qq][3] * inv);
        *reinterpret_cast<short4v*>(
            &ao[(((size_t)b * S + qb + qq * 16 + r) * H + h) * HD + d * 16 + g * 4]) = ov;
      }
    }
  }
}

extern "C" void kernel_launch(void* const* d_in, const int* in_sizes, int n_in,
                              void* d_out, int out_size, void* d_ws, size_t ws_size,
                              hipStream_t stream) {
  (void)in_sizes; (void)n_in; (void)out_size; (void)ws_size;
  const float* x    = (const float*)d_in[0];
  const float* cosb = (const float*)d_in[1];
  const float* sinb = (const float*)d_in[2];
  // d_in[3] = attn_mask (causal, unused)
  const float* wq   = (const float*)d_in[4];
  const float* wk   = (const float*)d_in[5];
  const float* wv   = (const float*)d_in[6];
  const float* wo   = (const float*)d_in[7];

  char* ws = (char*)d_ws;
  size_t off = 0;
  auto alloc = [&](size_t elems) {
    bf16* p = (bf16*)(ws + off);
    off = (off + elems * sizeof(bf16) + 255) & ~(size_t)255;
    return p;
  };
  bf16* xb    = alloc((size_t)M * D);
  bf16* wqkvb = alloc((size_t)QKV3 * D);   // wq | wk | wv rows, contiguous
  bf16* wob   = alloc((size_t)D * D);
  bf16* qkvb  = alloc((size_t)M * QKV3);   // fused Q|K activations (V goes to vt)
  bf16* vtb   = alloc((size_t)B * HK * HD * S);
  bf16* aob   = alloc((size_t)M * D);

  // fused cast (x, wq, wk, wv, wo -> xb, wqkvb, wob)
  cast_all_kernel<<<dim3(2048), dim3(256), 0, stream>>>(x, wq, wk, wv, wo, xb, wqkvb, wob);

  // fused QKV projection with in-epilogue K-rope and V-transpose
  gemm_qkv_kernel<<<dim3(QKV3 / 128, M / 128), 256, 0, stream>>>(xb, wqkvb, qkvb, vtb,
                                                                 cosb, sinb);

  // attention: 4-wave blocks, 32-row q-tiles, balanced front/back pairing
  attn_kernel<<<dim3(32, B * HK), 256, 0, stream>>>(qkvb, vtb, cosb, sinb, aob);

  // output projection (fp32 out)
  gemm_bt_kernel<true><<<dim3(D / 128, M / 128), 256, 0, stream>>>(aob, wob, d_out, D, D);
}

// Round 16
// 175.861 us; speedup vs baseline: 1.0674x; 1.0674x over previous
//
#include <hip/hip_runtime.h>
#include <hip/hip_bf16.h>
#include <math.h>

typedef __hip_bfloat16 bf16;
typedef __attribute__((ext_vector_type(8))) short bf16x8;
typedef __attribute__((ext_vector_type(4))) short short4v;
typedef __attribute__((ext_vector_type(4))) float f32x4;
typedef __attribute__((ext_vector_type(4))) unsigned int u32x4;

static constexpr int B = 2, S = 2048, D = 2048, H = 32, HK = 8, HD = 64;
static constexpr int M = B * S;           // 4096 tokens
static constexpr int NKV = HK * HD;       // 512
static constexpr int QKV3 = D + 2 * NKV;  // 3072 fused Q|K|V width
static constexpr float SCALE2 = 0.125f * 1.44269504f;  // folded into Q-rope in attn

__device__ __forceinline__ short bfbits(float x) {
  bf16 h = __float2bfloat16(x);
  return *reinterpret_cast<short*>(&h);
}

__device__ __forceinline__ float bf2f(short bits) {
  unsigned int u = ((unsigned int)(unsigned short)bits) << 16;
  return __builtin_bit_cast(float, u);
}

__device__ __forceinline__ void gl_lds16(const bf16* gp, bf16* lp) {
  __builtin_amdgcn_global_load_lds(
      (const __attribute__((address_space(1))) unsigned int*)(const void*)gp,
      (__attribute__((address_space(3))) unsigned int*)(void*)lp, 16, 0, 0);
}

// ---------------- fused cast fp32 -> bf16, 5 source regions ----------------
struct alignas(8) bf4 { bf16 v[4]; };
static constexpr int N4_X  = M * D / 4;        // 2097152
static constexpr int N4_WQ = D * D / 4;        // 1048576
static constexpr int N4_WK = NKV * D / 4;      // 262144
static constexpr int E0 = N4_X;
static constexpr int E1 = E0 + N4_WQ;
static constexpr int E2 = E1 + N4_WK;
static constexpr int E3 = E2 + N4_WK;
static constexpr int E4 = E3 + N4_WQ;
__global__ __launch_bounds__(256) void cast_all_kernel(const float* __restrict__ x,
                                                       const float* __restrict__ wq,
                                                       const float* __restrict__ wk,
                                                       const float* __restrict__ wv,
                                                       const float* __restrict__ wo,
                                                       bf16* __restrict__ xb,
                                                       bf16* __restrict__ wqkv,
                                                       bf16* __restrict__ wob) {
  int i = blockIdx.x * 256 + threadIdx.x;
  int stride = gridDim.x * 256;
  for (; i < E4; i += stride) {
    const float* s; bf16* d; int j;
    if (i < E0)      { s = x;  d = xb;   j = i; }
    else if (i < E1) { s = wq; d = wqkv; j = i - E0; }
    else if (i < E2) { s = wk; d = wqkv + (size_t)N4_WQ * 4; j = i - E1; }
    else if (i < E3) { s = wv; d = wqkv + (size_t)(N4_WQ + N4_WK) * 4; j = i - E2; }
    else             { s = wo; d = wob;  j = i - E3; }
    float4 f = reinterpret_cast<const float4*>(s)[j];
    bf4 o;
    o.v[0] = __float2bfloat16(f.x);
    o.v[1] = __float2bfloat16(f.y);
    o.v[2] = __float2bfloat16(f.z);
    o.v[3] = __float2bfloat16(f.w);
    reinterpret_cast<bf4*>(d)[j] = o;
  }
}

// ---------------- GEMM: C[M][N] = A[M][K] @ Bt[N][K]^T, bf16 in, f32 acc ----
template <bool OUT_F32>
__global__ __launch_bounds__(256) void gemm_bt_kernel(const bf16* __restrict__ A,
                                                      const bf16* __restrict__ Bt,
                                                      void* __restrict__ C,
                                                      int Ndim, int Kdim) {
  __shared__ __align__(16) bf16 As[128][64];
  __shared__ __align__(16) bf16 Bs[128][64];
  const int tid = threadIdx.x;
  const int lane = tid & 63;
  const int w = tid >> 6;
  const int wm = w >> 1, wn = w & 1;
  const int r16 = lane & 15, g = lane >> 4;
  const int bm = blockIdx.y, bn = blockIdx.x;
  f32x4 acc[4][4] = {};

  const int nk = Kdim >> 6;
  for (int kt = 0; kt < nk; ++kt) {
    __syncthreads();
#pragma unroll
    for (int i = 0; i < 4; ++i) {
      int u = tid + i * 256;           // 0..1023 : 128 rows x 8 16B-chunks
      int rr = u >> 3, c8 = u & 7;
      int c8s = c8 ^ (rr & 7);         // pre-swizzled source chunk
      gl_lds16(&A[(size_t)(bm * 128 + rr) * Kdim + kt * 64 + c8s * 8], &As[0][0] + (size_t)u * 8);
      gl_lds16(&Bt[(size_t)(bn * 128 + rr) * Kdim + kt * 64 + c8s * 8], &Bs[0][0] + (size_t)u * 8);
    }
    __syncthreads();
#pragma unroll
    for (int kc = 0; kc < 2; ++kc) {
      bf16x8 af[4], bfr[4];
      const int kq = kc * 4 + g;       // logical 16B-chunk index within BK=64
#pragma unroll
      for (int m = 0; m < 4; ++m) {
        int ra = wm * 64 + m * 16 + r16;
        af[m] = *reinterpret_cast<const bf16x8*>(&As[ra][(kq ^ (ra & 7)) * 8]);
        int rb = wn * 64 + m * 16 + r16;
        bfr[m] = *reinterpret_cast<const bf16x8*>(&Bs[rb][(kq ^ (rb & 7)) * 8]);
      }
#pragma unroll
      for (int m = 0; m < 4; ++m)
#pragma unroll
        for (int n = 0; n < 4; ++n)
          acc[m][n] = __builtin_amdgcn_mfma_f32_16x16x32_bf16(af[m], bfr[n], acc[m][n], 0, 0, 0);
    }
  }
  const int row0 = bm * 128 + wm * 64 + g * 4;
  const int col0 = bn * 128 + wn * 64 + r16;
#pragma unroll
  for (int m = 0; m < 4; ++m)
#pragma unroll
    for (int n = 0; n < 4; ++n)
#pragma unroll
      for (int j = 0; j < 4; ++j) {
        size_t idx = (size_t)(row0 + m * 16 + j) * Ndim + col0 + n * 16;
        if (OUT_F32)
          reinterpret_cast<float*>(C)[idx] = acc[m][n][j];
        else
          reinterpret_cast<bf16*>(C)[idx] = __float2bfloat16(acc[m][n][j]);
      }
}

// ---------------- RoPE for K heads only (slots 32..39 of qkv), in-place ------
__global__ __launch_bounds__(256) void rope_k_kernel(bf16* __restrict__ t,
                                                     const float* __restrict__ cosb,
                                                     const float* __restrict__ sinb) {
  int idx = blockIdx.x * 256 + threadIdx.x;  // B*S*8*32 threads exactly
  int i = idx & 31;
  int rest = idx >> 5;
  int hh = rest & 7;
  int s = (rest >> 3) % S;
  int b = rest / (8 * S);
  size_t base = ((size_t)b * S + s) * QKV3 + D + hh * HD;
  float x0 = __bfloat162float(t[base + i]);
  float x1 = __bfloat162float(t[base + i + 32]);
  float c = cosb[s * HD + i];
  float sn = sinb[s * HD + i];
  t[base + i] = __float2bfloat16(x0 * c - x1 * sn);
  t[base + i + 32] = __float2bfloat16(x1 * c + x0 * sn);
}

// ---------------- V transpose + slot-permute ----------------
// qkv[b][s][3072] cols 2560+ -> vt[b][hk][hd][S], permuted within each 32-kv
// block: pos p holds kv_local = (p>>3)*4 + (p&3) + ((p&4)<<2)
__global__ __launch_bounds__(256) void transpose_v_kernel(const bf16* __restrict__ qkv,
                                                          bf16* __restrict__ vt) {
  __shared__ bf16 tile[64][65];
  const int st = blockIdx.x;      // s-tile of 64
  const int bk = blockIdx.y;      // b*HK + hk
  const int b = bk >> 3, hk = bk & 7;
  const int tid = threadIdx.x;
#pragma unroll
  for (int i = 0; i < 16; ++i) {
    int idx = tid + i * 256;
    int rs = idx >> 6, c = idx & 63;
    tile[rs][c] = qkv[((size_t)b * S + st * 64 + rs) * QKV3 + (D + NKV) + hk * HD + c];
  }
  __syncthreads();
#pragma unroll
  for (int i = 0; i < 16; ++i) {
    int idx = tid + i * 256;
    int rh = idx >> 6, cs = idx & 63;
    int blk = cs >> 5, kvl = cs & 31;
    int pos = ((kvl >> 2) & 3) * 8 + ((kvl >> 4) << 2) + (kvl & 3);
    vt[(((size_t)b * HK + hk) * HD + rh) * S + st * 64 + blk * 32 + pos] = tile[cs][rh];
  }
}

// ---------------- causal flash attention (GQA), 4-wave LDS-staged ------------
// Block = 4 waves = 4 heads of one hk group, shared 32-row q-tile, balanced
// front/back pairing (512 blocks, 2/CU, 8 waves/CU). Every K/V ds_read feeds
// 2 MFMAs (2 q-fragments). 64-kv chunks double-buffered, chunk loop unrolled
// x2 (compile-time buffer index). No-max softmax (bounded scores), truncating
// P pack, l via ones-row MFMA, slot-permuted V for full-K=32 PV.
__global__ __launch_bounds__(256, 2) void attn_kernel(const bf16* __restrict__ qkv,
                                                      const bf16* __restrict__ vt,
                                                      const float* __restrict__ cosb,
                                                      const float* __restrict__ sinb,
                                                      bf16* __restrict__ ao) {
  __shared__ __align__(16) bf16 Ksh[2][64 * 64];
  __shared__ __align__(16) bf16 Vsh[2][64 * 64];
  const int u = blockIdx.x;        // 0..31
  const int y = blockIdx.y;        // b*HK + hk
  const int b = y >> 3, hk = y & 7;
  const int tid = threadIdx.x;
  const int w = tid >> 6;
  const int h = hk * 4 + w;        // this wave's head
  const int lane = tid & 63;
  const int r = lane & 15, g = lane >> 4;

  const bf16* qp  = qkv + ((size_t)b * S) * QKV3 + h * HD;         // Q (raw)
  const bf16* kvp = qkv + ((size_t)b * S) * QKV3 + D + hk * HD;    // K rows (stride 3072)
  const bf16* vtp = vt + (((size_t)b * HK + hk) * HD) * S;         // V^T rows (stride S)
  const int srow = tid >> 3;       // staging: 0..31 (+32 per iter)
  const int sc8 = tid & 7;

  bf16x8 ones;
#pragma unroll
  for (int j = 0; j < 8; ++j) ones[j] = (short)0x3F80;  // bf16 1.0

  auto stage64 = [&](int buf, int kv0) {
#pragma unroll
    for (int i = 0; i < 2; ++i) {
      int rr = srow + i * 32;
      int cs = sc8 ^ (rr & 7);
      gl_lds16(&kvp[(size_t)(kv0 + rr) * QKV3 + cs * 8], &Ksh[buf][((size_t)rr * 8 + sc8) * 8]);
    }
#pragma unroll
    for (int i = 0; i < 2; ++i) {
      int rr = srow + i * 32;
      int cs = sc8 ^ (rr & 7);
      gl_lds16(&vtp[(size_t)rr * S + kv0 + cs * 8], &Vsh[buf][((size_t)rr * 8 + sc8) * 8]);
    }
  };

  for (int pass = 0; pass < 2; ++pass) {
    const int qb = pass ? (2016 - u * 32) : (u * 32);
    // Q fragments (B-operand of S^T): col=q=r, k=hd=g*8+j (+32*hc)
    // RoPE + SCALE2 applied in-register: pair (hd, hd+32) = (hc0[j], hc1[j])
    bf16x8 qfr[2][2];
#pragma unroll
    for (int qq = 0; qq < 2; ++qq) {
      const int srowq = qb + qq * 16 + r;
      bf16x8 f0 = *reinterpret_cast<const bf16x8*>(&qp[(size_t)srowq * QKV3 + g * 8]);
      bf16x8 f1 = *reinterpret_cast<const bf16x8*>(&qp[(size_t)srowq * QKV3 + 32 + g * 8]);
      float4 c0 = reinterpret_cast<const float4*>(&cosb[(size_t)srowq * HD + g * 8])[0];
      float4 c1 = reinterpret_cast<const float4*>(&cosb[(size_t)srowq * HD + g * 8])[1];
      float4 s0 = reinterpret_cast<const float4*>(&sinb[(size_t)srowq * HD + g * 8])[0];
      float4 s1 = reinterpret_cast<const float4*>(&sinb[(size_t)srowq * HD + g * 8])[1];
      float cc[8] = {c0.x, c0.y, c0.z, c0.w, c1.x, c1.y, c1.z, c1.w};
      float ss[8] = {s0.x, s0.y, s0.z, s0.w, s1.x, s1.y, s1.z, s1.w};
#pragma unroll
      for (int j = 0; j < 8; ++j) {
        float x0 = bf2f(f0[j]), x1 = bf2f(f1[j]);
        qfr[qq][0][j] = bfbits((x0 * cc[j] - x1 * ss[j]) * SCALE2);
        qfr[qq][1][j] = bfbits((x1 * cc[j] + x0 * ss[j]) * SCALE2);
      }
    }

    f32x4 o[4][2] = {};
    f32x4 ol[2] = {};                // l accumulator (all rows identical)
    const int kv_end = qb + 32;
    const int nch = (kv_end + 63) >> 6;

    // one chunk: CUR is a literal at each call site -> LDS addresses hoist
    auto chunk = [&](int CUR, int cc, bool lastc) {
      const int kv0 = cc * 64;
      if (!lastc) stage64(CUR ^ 1, kv0 + 64);
      // S^T[kv][q] (exp2 domain): A=K (row=kv, k=hd), B=Q
      f32x4 scv[4][2] = {};
      __builtin_amdgcn_s_setprio(1);
#pragma unroll
      for (int f = 0; f < 4; ++f) {
        const int row = f * 16 + r;
#pragma unroll
        for (int hc = 0; hc < 2; ++hc) {
          bf16x8 kf = *reinterpret_cast<const bf16x8*>(
              &Ksh[CUR][(size_t)row * 64 + (((hc * 4 + g) ^ (r & 7)) * 8)]);
          scv[f][0] = __builtin_amdgcn_mfma_f32_16x16x32_bf16(kf, qfr[0][hc], scv[f][0], 0, 0, 0);
          scv[f][1] = __builtin_amdgcn_mfma_f32_16x16x32_bf16(kf, qfr[1][hc], scv[f][1], 0, 0, 0);
        }
      }
      __builtin_amdgcn_s_setprio(0);
      // causal mask (no max tracking: scores bounded)
      if (lastc) {
#pragma unroll
        for (int qq = 0; qq < 2; ++qq) {
          const int lim = qb + qq * 16 + r - kv0;
#pragma unroll
          for (int f = 0; f < 4; ++f)
#pragma unroll
            for (int j = 0; j < 4; ++j)
              if (f * 16 + g * 4 + j > lim) scv[f][qq][j] = -1e30f;
        }
      }
      // P = exp2(S^T), truncating pair-pack + PV + l per 32-kv block
#pragma unroll
      for (int blk = 0; blk < 2; ++blk) {
        u32x4 pk0, pk1;
#pragma unroll
        for (int pj = 0; pj < 4; ++pj) {
          const int f = blk * 2 + (pj >> 1);
          const int j0 = (pj & 1) * 2;
          float a0 = __builtin_amdgcn_exp2f(scv[f][0][j0]);
          float a1 = __builtin_amdgcn_exp2f(scv[f][0][j0 + 1]);
          pk0[pj] = (__builtin_bit_cast(unsigned int, a0) >> 16) |
                    (__builtin_bit_cast(unsigned int, a1) & 0xffff0000u);
          float b0 = __builtin_amdgcn_exp2f(scv[f][1][j0]);
          float b1 = __builtin_amdgcn_exp2f(scv[f][1][j0 + 1]);
          pk1[pj] = (__builtin_bit_cast(unsigned int, b0) >> 16) |
                    (__builtin_bit_cast(unsigned int, b1) & 0xffff0000u);
        }
        bf16x8 pb0 = __builtin_bit_cast(bf16x8, pk0);
        bf16x8 pb1 = __builtin_bit_cast(bf16x8, pk1);
        __builtin_amdgcn_s_setprio(1);
        ol[0] = __builtin_amdgcn_mfma_f32_16x16x32_bf16(ones, pb0, ol[0], 0, 0, 0);
        ol[1] = __builtin_amdgcn_mfma_f32_16x16x32_bf16(ones, pb1, ol[1], 0, 0, 0);
#pragma unroll
        for (int d = 0; d < 4; ++d) {
          bf16x8 vf = *reinterpret_cast<const bf16x8*>(
              &Vsh[CUR][(size_t)(d * 16 + r) * 64 + (((blk * 4 + g) ^ (r & 7)) * 8)]);
          o[d][0] = __builtin_amdgcn_mfma_f32_16x16x32_bf16(vf, pb0, o[d][0], 0, 0, 0);
          o[d][1] = __builtin_amdgcn_mfma_f32_16x16x32_bf16(vf, pb1, o[d][1], 0, 0, 0);
        }
        __builtin_amdgcn_s_setprio(0);
      }
      __syncthreads();   // drains stage(cc+1) + guards buffer reuse
    };

    stage64(0, 0);
    __syncthreads();
    int c = 0;
    for (; c + 2 <= nch; c += 2) {
      chunk(0, c, c == nch - 1);
      chunk(1, c + 1, c + 1 == nch - 1);
    }
    if (c < nch) chunk(0, c, true);

    // epilogue: l lives in every lane (all MFMA rows identical)
#pragma unroll
    for (int qq = 0; qq < 2; ++qq) {
      float inv = 1.0f / ol[qq][0];
#pragma unroll
      for (int d = 0; d < 4; ++d) {
        short4v ov;
        ov[0] = bfbits(o[d][qq][0] * inv);
        ov[1] = bfbits(o[d][qq][1] * inv);
        ov[2] = bfbits(o[d][qq][2] * inv);
        ov[3] = bfbits(o[d][qq][3] * inv);
        *reinterpret_cast<short4v*>(
            &ao[(((size_t)b * S + qb + qq * 16 + r) * H + h) * HD + d * 16 + g * 4]) = ov;
      }
    }
  }
}

extern "C" void kernel_launch(void* const* d_in, const int* in_sizes, int n_in,
                              void* d_out, int out_size, void* d_ws, size_t ws_size,
                              hipStream_t stream) {
  (void)in_sizes; (void)n_in; (void)out_size; (void)ws_size;
  const float* x    = (const float*)d_in[0];
  const float* cosb = (const float*)d_in[1];
  const float* sinb = (const float*)d_in[2];
  // d_in[3] = attn_mask (causal, unused)
  const float* wq   = (const float*)d_in[4];
  const float* wk   = (const float*)d_in[5];
  const float* wv   = (const float*)d_in[6];
  const float* wo   = (const float*)d_in[7];

  char* ws = (char*)d_ws;
  size_t off = 0;
  auto alloc = [&](size_t elems) {
    bf16* p = (bf16*)(ws + off);
    off = (off + elems * sizeof(bf16) + 255) & ~(size_t)255;
    return p;
  };
  bf16* xb    = alloc((size_t)M * D);
  bf16* wqkvb = alloc((size_t)QKV3 * D);   // wq | wk | wv rows, contiguous
  bf16* wob   = alloc((size_t)D * D);
  bf16* qkvb  = alloc((size_t)M * QKV3);   // fused Q|K|V activations
  bf16* vtb   = alloc((size_t)B * HK * HD * S);
  bf16* aob   = alloc((size_t)M * D);

  // fused cast (x, wq, wk, wv, wo -> xb, wqkvb, wob)
  cast_all_kernel<<<dim3(2048), dim3(256), 0, stream>>>(x, wq, wk, wv, wo, xb, wqkvb, wob);

  // fused QKV projection: [M][3072] = xb @ wqkvb^T
  gemm_bt_kernel<false><<<dim3(QKV3 / 128, M / 128), 256, 0, stream>>>(xb, wqkvb, qkvb, QKV3, D);

  // rope K heads only (Q is roped in-register inside attn)
  rope_k_kernel<<<dim3(B * S * 8 * 32 / 256), 256, 0, stream>>>(qkvb, cosb, sinb);

  // v transpose (+ slot permute) for PV A-operand
  transpose_v_kernel<<<dim3(S / 64, B * HK), 256, 0, stream>>>(qkvb, vtb);

  // attention: 4-wave blocks, 32-row q-tiles, balanced front/back pairing
  attn_kernel<<<dim3(32, B * HK), 256, 0, stream>>>(qkvb, vtb, cosb, sinb, aob);

  // output projection (fp32 out)
  gemm_bt_kernel<true><<<dim3(D / 128, M / 128), 256, 0, stream>>>(aob, wob, d_out, D, D);
}